// Round 8
// baseline (266.205 us; speedup 1.0000x reference)
//
#include <hip/hip_runtime.h>
#include <math.h>

#define BB 32
#define QQ 300
#define CC 91
#define TOPK 50
#define NKEEP 256
#define QC (QQ * CC)        // 27300
#define QC4 (QC / 4)        // 6825 float4s (exact)
#define NT 256              // threads per block (4 waves)
#define CAP 1024            // max boundary-bin candidates for the fast path (expected ~620)

// output layout (flat float32, reference return order)
#define OFF_SCORES ((size_t)0)
#define OFF_LABELS ((size_t)1600)
#define OFF_BOXES  ((size_t)3200)
#define OFF_MASKS  ((size_t)9600)
#define OFF_SI     ((size_t)26224000)
#define OFF_LI     ((size_t)26225600)
#define OFF_LA     ((size_t)26227200)

__device__ __forceinline__ uint32_t fkey(float f) {
    uint32_t u = __float_as_uint(f);
    return (u >> 31) ? ~u : (u | 0x80000000u);
}

// wave-0 helper: given 256-bin counts, pick boundary bin for the kth largest.
__device__ __forceinline__ void pick_boundary(const uint32_t* bins, int kth, int lane,
                                              uint32_t* sBin, int* sNeed, int* sCnt) {
    uint4 h4 = *(const uint4*)&bins[lane * 4];
    uint32_t s3 = h4.w;
    uint32_t s2 = h4.z + s3;
    uint32_t s1 = h4.y + s2;
    uint32_t s0 = h4.x + s1;
    uint32_t inc = s0;
#pragma unroll
    for (int off = 1; off < 64; off <<= 1) {
        uint32_t v = __shfl_down(inc, off);
        if (lane + off < 64) inc += v;
    }
    uint32_t higher = inc - s0;   // strictly-higher lanes' total
    uint32_t sarr[4] = {s0, s1, s2, s3};
    uint32_t harr[4] = {h4.x, h4.y, h4.z, h4.w};
#pragma unroll
    for (int c = 0; c < 4; ++c) {
        int cge = (int)(sarr[c] + higher);
        int cgt = cge - (int)harr[c];
        if (cge >= kth && cgt < kth) {
            *sBin = (uint32_t)(lane * 4 + c);
            *sNeed = kth - cgt;
            *sCnt = (int)harr[c];
        }
    }
}

// LDS union: select phase (22.4 KB) then mask phase (26.2 KB) -> 6 blocks/CU.
union alignas(16) Smem {
    struct {
        uint32_t hw[4 * 256];          // per-wave privatized histograms (4 KB)
        uint32_t scn[256];
        uint32_t h2[256];
        uint32_t candK[2][CAP];        // 8 KB
        int      candI[2][CAP];        // 8 KB
        uint32_t cKey[TOPK];
        int      cIdx[TOPK];
    } s;
    struct {
        float sD[23 * 128];            // DCT rows (11.5 KB)
        float sT[23 * 128];            // stage-1 result (11.5 KB)
        float sB[23 * 24];             // zigzag-scattered coefficients
        int   sZZ[256];
        float redv[4]; int redi[4];
        float redmn[4], redmx[4];
    } m;
};

// ONE plain dispatch, 1600 independent blocks. Block (j,b) redundantly selects batch b's
// top-50 (deterministic: the ranked set is atomic-order-independent), emits the rank-j
// outputs, then computes unit (b,j)'s mask. NO workspace, NO cross-block communication,
// NO cooperative launch -- nothing subject to XCD L2 non-coherence (R6/R7 failure mode).
__global__ __launch_bounds__(NT) void fused_all(const float* __restrict__ logits,
                                                const float* __restrict__ bbox,
                                                const float* __restrict__ vec,
                                                const float* __restrict__ interms,
                                                const float* __restrict__ actions,
                                                const int* __restrict__ tsz,
                                                float* __restrict__ out) {
    int j = blockIdx.x;      // rank 0..49
    int b = blockIdx.y;      // batch 0..31
    int t = threadIdx.x;
    int lane = t & 63, w4 = t >> 6;

    __shared__ Smem sm;
    __shared__ uint32_t sP;
    __shared__ int sNeed, sCnt, cntTop, cntN, cntE, sMin, sQ;

    const float4* base4 = (const float4*)(logits + (size_t)b * QC);

    // ======== select: own pass-0 byte histogram ========
    for (int i = t; i < 4 * 256; i += NT) sm.s.hw[i] = 0;
    __syncthreads();
    {
        uint32_t* myh = &sm.s.hw[w4 * 256];
        for (int p4 = t; p4 < QC4; p4 += NT) {
            float4 v = base4[p4];
            atomicAdd(&myh[fkey(v.x) >> 24], 1u);
            atomicAdd(&myh[fkey(v.y) >> 24], 1u);
            atomicAdd(&myh[fkey(v.z) >> 24], 1u);
            atomicAdd(&myh[fkey(v.w) >> 24], 1u);
        }
    }
    __syncthreads();
    if (t < 256) sm.s.scn[t] = sm.s.hw[t] + sm.s.hw[256 + t] + sm.s.hw[512 + t] + sm.s.hw[768 + t];
    if (t == 0) { cntTop = 0; cntN = 0; cntE = 0; }
    __syncthreads();
    if (t < 64) pick_boundary(sm.s.scn, TOPK, lane, &sP, &sNeed, &sCnt);
    __syncthreads();
    uint32_t P0 = sP << 24;     // boundary byte as full-key prefix
    int need = sNeed;           // how many to take from the boundary bin
    int nC0 = sCnt;             // boundary-bin population

    if (nC0 <= CAP) {
        // ======== FAST PATH (R5-verified logic, NT strides) ========
        for (int p4 = t; p4 < QC4; p4 += NT) {
            float4 v = base4[p4];
            uint32_t kk[4] = {fkey(v.x), fkey(v.y), fkey(v.z), fkey(v.w)};
#pragma unroll
            for (int c = 0; c < 4; ++c) {
                uint32_t hb = kk[c] & 0xFF000000u;
                if (hb > P0) {
                    int pos = atomicAdd(&cntTop, 1);
                    sm.s.cKey[pos] = kk[c]; sm.s.cIdx[pos] = 4 * p4 + c;
                } else if (hb == P0) {
                    int pos = atomicAdd(&cntN, 1);
                    sm.s.candK[0][pos] = kk[c]; sm.s.candI[0][pos] = 4 * p4 + c;
                }
            }
        }
        __syncthreads();
        int nc = cntN, cur = 0;

        // refine with 8-bit radix levels over candidates only (LDS-resident)
        for (int level = 1; level <= 3; ++level) {
            if (nc <= need) break;       // invariant nc >= need => nc == need
            int shift = 24 - 8 * level;
            if (t < 256) sm.s.h2[t] = 0;
            if (t == 0) cntN = 0;
            __syncthreads();
            for (int j2 = t; j2 < nc; j2 += NT)
                atomicAdd(&sm.s.h2[(sm.s.candK[cur][j2] >> shift) & 255u], 1u);
            __syncthreads();
            if (t < 64) pick_boundary(sm.s.h2, need, lane, &sP, &sNeed, &sCnt);
            __syncthreads();
            uint32_t sub = sP;
            int needN = sNeed;
            for (int j2 = t; j2 < nc; j2 += NT) {
                uint32_t k2 = sm.s.candK[cur][j2]; int i2 = sm.s.candI[cur][j2];
                uint32_t sb = (k2 >> shift) & 255u;
                if (sb > sub) {
                    int pos = atomicAdd(&cntTop, 1);
                    sm.s.cKey[pos] = k2; sm.s.cIdx[pos] = i2;
                } else if (sb == sub) {
                    int pos = atomicAdd(&cntN, 1);
                    sm.s.candK[cur ^ 1][pos] = k2; sm.s.candI[cur ^ 1][pos] = i2;
                }
            }
            __syncthreads();
            nc = cntN; need = needN; cur ^= 1;
        }

        int base = cntTop;   // uniform (post-barrier)
        if (nc <= need) {
            for (int j2 = t; j2 < nc; j2 += NT) {
                sm.s.cKey[base + j2] = sm.s.candK[cur][j2];
                sm.s.cIdx[base + j2] = sm.s.candI[cur][j2];
            }
        } else {
            // survivors share the exact full key: take `need` smallest indices
            for (int j2 = t; j2 < nc; j2 += NT) {
                int my = sm.s.candI[cur][j2];
                int rank = 0;
                for (int m = 0; m < nc; ++m) rank += (sm.s.candI[cur][m] < my);
                if (rank < need) { sm.s.cKey[base + rank] = sm.s.candK[cur][j2]; sm.s.cIdx[base + rank] = my; }
            }
        }
        __syncthreads();
    } else {
        // ======== SLOW FALLBACK (pathological; global re-read per pass) ========
        uint32_t Pfull = P0;
        int kth = need;
        uint32_t* myh = &sm.s.hw[w4 * 256];
        for (int pass = 1; pass < 4; ++pass) {
            int shift = 24 - 8 * pass;
            for (int i2 = t; i2 < 4 * 256; i2 += NT) sm.s.hw[i2] = 0;
            __syncthreads();
            uint32_t pmask = 0xFFFFFFFFu << (shift + 8);
            for (int p4 = t; p4 < QC4; p4 += NT) {
                float4 v = base4[p4];
                uint32_t kk[4] = {fkey(v.x), fkey(v.y), fkey(v.z), fkey(v.w)};
#pragma unroll
                for (int c = 0; c < 4; ++c)
                    if ((kk[c] & pmask) == Pfull) atomicAdd(&myh[(kk[c] >> shift) & 255u], 1u);
            }
            __syncthreads();
            if (t < 256) sm.s.scn[t] = sm.s.hw[t] + sm.s.hw[256 + t] + sm.s.hw[512 + t] + sm.s.hw[768 + t];
            __syncthreads();
            if (t < 64) pick_boundary(sm.s.scn, kth, lane, &sP, &sNeed, &sCnt);
            __syncthreads();
            Pfull |= (sP << shift);
            kth = sNeed;
        }
        if (t == 0) { cntTop = 0; cntE = 0; }
        __syncthreads();
        for (int p4 = t; p4 < QC4; p4 += NT) {
            float4 v = base4[p4];
            uint32_t kk[4] = {fkey(v.x), fkey(v.y), fkey(v.z), fkey(v.w)};
#pragma unroll
            for (int c = 0; c < 4; ++c) {
                if (kk[c] > Pfull) {
                    int pos = atomicAdd(&cntTop, 1);
                    sm.s.cKey[pos] = kk[c]; sm.s.cIdx[pos] = 4 * p4 + c;
                } else if (kk[c] == Pfull) {
                    int pos = atomicAdd(&cntE, 1);
                    if (pos < CAP) sm.s.candI[0][pos] = 4 * p4 + c;
                }
            }
        }
        __syncthreads();
        int cgt2 = cntTop;   // == TOPK - kth
        int ne = cntE;
        if (ne <= CAP) {
            for (int j2 = t; j2 < ne; j2 += NT) {
                int my = sm.s.candI[0][j2];
                int rank = 0;
                for (int m = 0; m < ne; ++m) rank += (sm.s.candI[0][m] < my);
                if (rank < kth) { sm.s.cKey[cgt2 + rank] = Pfull; sm.s.cIdx[cgt2 + rank] = my; }
            }
            __syncthreads();
        } else {
            int prevMin = -1;
            for (int r = 0; r < kth; ++r) {
                if (t == 0) sMin = 0x7fffffff;
                __syncthreads();
                int loc = 0x7fffffff;
                for (int p4 = t; p4 < QC4; p4 += NT) {
                    float4 v = base4[p4];
                    uint32_t kk[4] = {fkey(v.x), fkey(v.y), fkey(v.z), fkey(v.w)};
#pragma unroll
                    for (int c = 0; c < 4; ++c) {
                        int idx = 4 * p4 + c;
                        if (kk[c] == Pfull && idx > prevMin) loc = min(loc, idx);
                    }
                }
                atomicMin(&sMin, loc);
                __syncthreads();
                prevMin = sMin;
                if (t == 0) { sm.s.cKey[cgt2 + r] = Pfull; sm.s.cIdx[cgt2 + r] = prevMin; }
                __syncthreads();
            }
        }
    }

    // ======== rank the 50 winners; this block emits ONLY rank j ========
    if (t < TOPK) {
        uint32_t myk = sm.s.cKey[t]; int myi = sm.s.cIdx[t];
        int rank = 0;
        for (int m = 0; m < TOPK; ++m) {
            uint32_t ok = sm.s.cKey[m]; int oi = sm.s.cIdx[m];
            rank += (ok > myk) || (ok == myk && oi < myi);
        }
        if (rank == j) {
            uint32_t u = (myk >> 31) ? (myk & 0x7fffffffu) : ~myk;
            float val = __uint_as_float(u);
            int q = myi / CC;
            int label = myi - q * CC;
            out[OFF_SCORES + b * TOPK + j] = 1.0f / (1.0f + expf(-val));
            out[OFF_LABELS + b * TOPK + j] = (float)label;
            const float* bbp = bbox + ((size_t)(b * QQ + q)) * 4;
            float cx = bbp[0], cy = bbp[1], bw = bbp[2], bh = bbp[3];
            float ih = (float)tsz[b * 2 + 0];
            float iw = (float)tsz[b * 2 + 1];
            float* bo = out + OFF_BOXES + ((size_t)(b * TOPK + j)) * 4;
            bo[0] = (cx - 0.5f * bw) * iw;
            bo[1] = (cy - 0.5f * bh) * ih;
            bo[2] = (cx + 0.5f * bw) * iw;
            bo[3] = (cy + 0.5f * bh) * ih;
            sQ = q;
        }
    }
    if (j == 0 && t == 0) {
        const float* ap = actions + (size_t)b * 10;
        float bv = ap[0]; int bi = 0;
        for (int i = 1; i < 10; ++i) { if (ap[i] > bv) { bv = ap[i]; bi = i; } }
        out[OFF_LA + b] = (float)bi;
    }
    __syncthreads();   // sQ visible; select-LDS reads complete (union flips to mask)
    int q = sQ;

    // ======== mask part (R5-verified body; tables rebuilt per block in LDS) ========
    for (int idx = t; idx < 23 * 128; idx += NT) {
        int k = idx >> 7, m = idx & 127;
        double v = cos((M_PI * (2.0 * (double)m + 1.0) * (double)k) / 256.0) * 0.125;
        if (k == 0) v *= sqrt(0.5);
        sm.m.sD[idx] = (float)v;
    }
    {
        int jj = t;
        int ss = 0;
        while ((ss + 1) * (ss + 2) / 2 <= jj) ++ss;
        int o = jj - ss * (ss + 1) / 2;
        int r = (ss & 1) ? o : (ss - o);
        int ccol = ss - r;
        sm.m.sZZ[t] = (r << 5) | ccol;
    }
    for (int i = t; i < 23 * 24; i += NT) sm.m.sB[i] = 0.0f;
    __syncthreads();

    // scatter the 256 kept coefficients into zigzag positions (k+l <= 22)
    {
        int kl = sm.m.sZZ[t];
        float x = vec[((size_t)(b * QQ + q)) * NKEEP + t];
        sm.m.sB[(kl >> 5) * 24 + (kl & 31)] = x;
    }

    // interms argmax/max over 91 classes (sigmoid is monotone)
    {
        float x = (t < CC) ? interms[((size_t)(b * QQ + q)) * CC + t] : -INFINITY;
        int xi = (t < CC) ? t : 0x7fffffff;
#pragma unroll
        for (int off = 32; off >= 1; off >>= 1) {
            float ov = __shfl_down(x, off);
            int   oi = __shfl_down(xi, off);
            bool better = (ov > x) || (ov == x && oi < xi);
            x = better ? ov : x;
            xi = better ? oi : xi;
        }
        if (lane == 0) { sm.m.redv[w4] = x; sm.m.redi[w4] = xi; }
    }
    __syncthreads();   // guards sB scatter + redv/redi

    if (t == 0) {
        float gv = sm.m.redv[0]; int gi = sm.m.redi[0];
        for (int k = 1; k < 4; ++k) {
            bool better = (sm.m.redv[k] > gv) || (sm.m.redv[k] == gv && sm.m.redi[k] < gi);
            gv = better ? sm.m.redv[k] : gv;
            gi = better ? sm.m.redi[k] : gi;
        }
        out[OFF_SI + (size_t)b * TOPK + j] = 1.0f / (1.0f + expf(-gv));
        out[OFF_LI + (size_t)b * TOPK + j] = (float)gi;
    }

    // stage 1: T[l][n] = sum_{k <= 22-l} D[k][n] * B[k][l]  (triangular)
    {
        int n = t & 127, h = t >> 7;
        float Dn[23];
#pragma unroll
        for (int k = 0; k < 23; ++k) Dn[k] = sm.m.sD[k * 128 + n];
#define S1L(L) { float a1 = 0.0f; \
    _Pragma("unroll") \
    for (int k = 0; k <= 22 - (L); ++k) a1 += Dn[k] * sm.m.sB[k * 24 + (L)]; \
    sm.m.sT[(L) * 128 + n] = a1; }
        if (h == 0) {
            S1L(0) S1L(2) S1L(4) S1L(6) S1L(8) S1L(10)
            S1L(12) S1L(14) S1L(16) S1L(18) S1L(20) S1L(22)
        } else {
            S1L(1) S1L(3) S1L(5) S1L(7) S1L(9) S1L(11)
            S1L(13) S1L(15) S1L(17) S1L(19) S1L(21)
        }
#undef S1L
    }
    __syncthreads();

    // stage 2: out[n][m] = sum_l T[l][n] * D[l][m]  -- 8x8 register tile per thread
    int tr = t >> 4, tc = t & 15;
    float acc[8][8];
#pragma unroll
    for (int a = 0; a < 8; ++a)
#pragma unroll
        for (int c = 0; c < 8; ++c) acc[a][c] = 0.0f;

#pragma unroll 4
    for (int l = 0; l < 23; ++l) {
        const float4 Ta = *(const float4*)&sm.m.sT[l * 128 + tr * 8];
        const float4 Tb = *(const float4*)&sm.m.sT[l * 128 + tr * 8 + 4];
        const float4 Da = *(const float4*)&sm.m.sD[l * 128 + tc * 8];
        const float4 Db = *(const float4*)&sm.m.sD[l * 128 + tc * 8 + 4];
        float Tv[8] = {Ta.x, Ta.y, Ta.z, Ta.w, Tb.x, Tb.y, Tb.z, Tb.w};
        float Dv[8] = {Da.x, Da.y, Da.z, Da.w, Db.x, Db.y, Db.z, Db.w};
#pragma unroll
        for (int a = 0; a < 8; ++a)
#pragma unroll
            for (int c = 0; c < 8; ++c) acc[a][c] += Tv[a] * Dv[c];
    }

    // block min/max
    float mn = acc[0][0], mx = acc[0][0];
#pragma unroll
    for (int a = 0; a < 8; ++a)
#pragma unroll
        for (int c = 0; c < 8; ++c) {
            mn = fminf(mn, acc[a][c]);
            mx = fmaxf(mx, acc[a][c]);
        }
#pragma unroll
    for (int off = 32; off >= 1; off >>= 1) {
        mn = fminf(mn, __shfl_down(mn, off));
        mx = fmaxf(mx, __shfl_down(mx, off));
    }
    if (lane == 0) { sm.m.redmn[w4] = mn; sm.m.redmx[w4] = mx; }
    __syncthreads();
    float gmn = fminf(fminf(sm.m.redmn[0], sm.m.redmn[1]), fminf(sm.m.redmn[2], sm.m.redmn[3]));
    float gmx = fmaxf(fmaxf(sm.m.redmx[0], sm.m.redmx[1]), fmaxf(sm.m.redmx[2], sm.m.redmx[3]));
    float thr = 0.5f * (gmx + gmn);

    size_t bse = OFF_MASKS + ((size_t)(b * TOPK + j)) * 16384 + (size_t)tc * 8;
#pragma unroll
    for (int a = 0; a < 8; ++a) {
        int n = tr * 8 + a;
        float4 w0 = make_float4(acc[a][0] > thr ? 1.0f : 0.0f,
                                acc[a][1] > thr ? 1.0f : 0.0f,
                                acc[a][2] > thr ? 1.0f : 0.0f,
                                acc[a][3] > thr ? 1.0f : 0.0f);
        float4 w1 = make_float4(acc[a][4] > thr ? 1.0f : 0.0f,
                                acc[a][5] > thr ? 1.0f : 0.0f,
                                acc[a][6] > thr ? 1.0f : 0.0f,
                                acc[a][7] > thr ? 1.0f : 0.0f);
        *(float4*)&out[bse + (size_t)n * 128]     = w0;
        *(float4*)&out[bse + (size_t)n * 128 + 4] = w1;
    }
}

extern "C" void kernel_launch(void* const* d_in, const int* in_sizes, int n_in,
                              void* d_out, int out_size, void* d_ws, size_t ws_size,
                              hipStream_t stream) {
    const float* logits  = (const float*)d_in[0];
    const float* bbox    = (const float*)d_in[1];
    const float* vec     = (const float*)d_in[2];
    const float* interms = (const float*)d_in[3];
    const float* actions = (const float*)d_in[4];
    const int*   tsz     = (const int*)d_in[5];
    float* out = (float*)d_out;

    hipLaunchKernelGGL(fused_all, dim3(TOPK, BB), dim3(NT), 0, stream,
                       logits, bbox, vec, interms, actions, tsz, out);
}

// Round 9
// 164.918 us; speedup vs baseline: 1.6142x; 1.6142x over previous
//
#include <hip/hip_runtime.h>
#include <math.h>

#define BB 32
#define QQ 300
#define CC 91
#define TOPK 50
#define NKEEP 256
#define QC (QQ * CC)        // 27300
#define QC4 (QC / 4)        // 6825 float4s (exact)
#define NWAVE 16
#define CAP 1024            // max boundary-bin candidates for the fast path (expected ~620)

// output layout (flat float32, reference return order)
#define OFF_SCORES ((size_t)0)
#define OFF_LABELS ((size_t)1600)
#define OFF_BOXES  ((size_t)3200)
#define OFF_MASKS  ((size_t)9600)
#define OFF_SI     ((size_t)26224000)
#define OFF_LI     ((size_t)26225600)
#define OFF_LA     ((size_t)26227200)

__device__ __forceinline__ uint32_t fkey(float f) {
    uint32_t u = __float_as_uint(f);
    return (u >> 31) ? ~u : (u | 0x80000000u);
}

// wave-0 helper: given 256-bin counts, pick boundary bin for the kth largest.
__device__ __forceinline__ void pick_boundary(const uint32_t* bins, int kth, int lane,
                                              uint32_t* sBin, int* sNeed, int* sCnt) {
    uint4 h4 = *(const uint4*)&bins[lane * 4];
    uint32_t s3 = h4.w;
    uint32_t s2 = h4.z + s3;
    uint32_t s1 = h4.y + s2;
    uint32_t s0 = h4.x + s1;
    uint32_t inc = s0;
#pragma unroll
    for (int off = 1; off < 64; off <<= 1) {
        uint32_t v = __shfl_down(inc, off);
        if (lane + off < 64) inc += v;
    }
    uint32_t higher = inc - s0;   // strictly-higher lanes' total
    uint32_t sarr[4] = {s0, s1, s2, s3};
    uint32_t harr[4] = {h4.x, h4.y, h4.z, h4.w};
#pragma unroll
    for (int c = 0; c < 4; ++c) {
        int cge = (int)(sarr[c] + higher);
        int cgt = cge - (int)harr[c];
        if (cge >= kth && cgt < kth) {
            *sBin = (uint32_t)(lane * 4 + c);
            *sNeed = kth - cgt;
            *sCnt = (int)harr[c];
        }
    }
}

// ---------------- K1: table init + own pass-0 hist + select + emit (32 blocks x 1024) ----------
// Merged hist+select: saves one dispatch (~15us gap measured in R8: 266-173-63) plus the
// hist kernel. No per-thread key cache (R2's 81.5us was its scratch spill at 64-VGPR cap).
__global__ __launch_bounds__(1024) void topk_select(const float* __restrict__ logits,
                                                    const float* __restrict__ bbox,
                                                    const float* __restrict__ actions,
                                                    const int* __restrict__ tsz,
                                                    float* __restrict__ out,
                                                    int* __restrict__ wsQ,
                                                    float* __restrict__ wsD,
                                                    int* __restrict__ wsZZ) {
    int b = blockIdx.x;
    int t = threadIdx.x;
    int lane = t & 63, w = t >> 6;

    // ---- table init spread over blocks 0..7 (fp64 cos, matches numpy; R4-verified code) ----
    if (b < 8) {
        int lo = b * 368, hi = lo + 368;
        if (hi > 23 * 128) hi = 23 * 128;
        for (int idx = lo + t; idx < hi; idx += 1024) {
            int k = idx >> 7, m = idx & 127;
            double v = cos((M_PI * (2.0 * (double)m + 1.0) * (double)k) / 256.0) * 0.125;
            if (k == 0) v *= sqrt(0.5);
            wsD[idx] = (float)v;
        }
        if (b == 0 && t < NKEEP) {
            int j = t;
            int ss = 0;
            while ((ss + 1) * (ss + 2) / 2 <= j) ++ss;
            int o = j - ss * (ss + 1) / 2;
            int r = (ss & 1) ? o : (ss - o);
            int c = ss - r;
            wsZZ[j] = (r << 5) | c;
        }
    }

    __shared__ uint32_t hw[NWAVE * 256];                          // wave-private hists (16 KB)
    __shared__ __attribute__((aligned(16))) uint32_t scn[256];
    __shared__ __attribute__((aligned(16))) uint32_t h2[256];
    __shared__ uint32_t sP;
    __shared__ int      sNeed, sCnt;
    __shared__ uint32_t cKey[TOPK];
    __shared__ int      cIdx[TOPK];
    __shared__ int      cntTop, cntN, cntE, sMin;
    __shared__ uint32_t candK[2][CAP];                            // 8 KB
    __shared__ int      candI[2][CAP];                            // 8 KB

    const float4* base4 = (const float4*)(logits + (size_t)b * QC);

    // ---- pass-0 byte histogram (16 wave-private copies; R2-verified pattern) ----
    for (int i = t; i < NWAVE * 256; i += 1024) hw[i] = 0;
    if (t == 0) { cntTop = 0; cntN = 0; cntE = 0; }
    __syncthreads();
    {
        uint32_t* myh = &hw[w * 256];
        for (int p4 = t; p4 < QC4; p4 += 1024) {
            float4 v = base4[p4];
            atomicAdd(&myh[fkey(v.x) >> 24], 1u);
            atomicAdd(&myh[fkey(v.y) >> 24], 1u);
            atomicAdd(&myh[fkey(v.z) >> 24], 1u);
            atomicAdd(&myh[fkey(v.w) >> 24], 1u);
        }
    }
    __syncthreads();
    if (t < 256) {
        uint32_t s = 0;
#pragma unroll
        for (int ww = 0; ww < NWAVE; ++ww) s += hw[ww * 256 + t];
        scn[t] = s;
    }
    __syncthreads();
    if (t < 64) pick_boundary(scn, TOPK, lane, &sP, &sNeed, &sCnt);
    __syncthreads();
    uint32_t P0 = sP << 24;     // boundary byte as full-key prefix
    int need = sNeed;           // how many to take from the boundary bin
    int nC0 = sCnt;             // boundary-bin population

    if (nC0 <= CAP) {
        // ============ FAST PATH (R5-verified) ============
        for (int p4 = t; p4 < QC4; p4 += 1024) {
            float4 v = base4[p4];
            uint32_t kk[4] = {fkey(v.x), fkey(v.y), fkey(v.z), fkey(v.w)};
#pragma unroll
            for (int c = 0; c < 4; ++c) {
                uint32_t hb = kk[c] & 0xFF000000u;
                if (hb > P0) {
                    int pos = atomicAdd(&cntTop, 1);
                    cKey[pos] = kk[c]; cIdx[pos] = 4 * p4 + c;
                } else if (hb == P0) {
                    int pos = atomicAdd(&cntN, 1);
                    candK[0][pos] = kk[c]; candI[0][pos] = 4 * p4 + c;
                }
            }
        }
        __syncthreads();
        int nc = cntN, cur = 0;

        // refine with 8-bit radix levels over candidates only (LDS-resident)
        for (int level = 1; level <= 3; ++level) {
            if (nc <= need) break;       // invariant nc >= need => nc == need
            int shift = 24 - 8 * level;
            if (t < 256) h2[t] = 0;
            if (t == 0) cntN = 0;
            __syncthreads();
            for (int j2 = t; j2 < nc; j2 += 1024)
                atomicAdd(&h2[(candK[cur][j2] >> shift) & 255u], 1u);
            __syncthreads();
            if (t < 64) pick_boundary(h2, need, lane, &sP, &sNeed, &sCnt);
            __syncthreads();
            uint32_t sub = sP;
            int needN = sNeed;
            for (int j2 = t; j2 < nc; j2 += 1024) {
                uint32_t k2 = candK[cur][j2]; int i2 = candI[cur][j2];
                uint32_t sb = (k2 >> shift) & 255u;
                if (sb > sub) {
                    int pos = atomicAdd(&cntTop, 1);
                    cKey[pos] = k2; cIdx[pos] = i2;
                } else if (sb == sub) {
                    int pos = atomicAdd(&cntN, 1);
                    candK[cur ^ 1][pos] = k2; candI[cur ^ 1][pos] = i2;
                }
            }
            __syncthreads();
            nc = cntN; need = needN; cur ^= 1;
        }

        int base = cntTop;   // uniform (post-barrier)
        if (nc <= need) {
            for (int j2 = t; j2 < nc; j2 += 1024) {
                cKey[base + j2] = candK[cur][j2];
                cIdx[base + j2] = candI[cur][j2];
            }
        } else {
            // survivors share the exact full key: take `need` smallest indices
            for (int j2 = t; j2 < nc; j2 += 1024) {
                int my = candI[cur][j2];
                int rank = 0;
                for (int m = 0; m < nc; ++m) rank += (candI[cur][m] < my);
                if (rank < need) { cKey[base + rank] = candK[cur][j2]; cIdx[base + rank] = my; }
            }
        }
        __syncthreads();
    } else {
        // ============ SLOW FALLBACK (R5-verified; global re-read per pass) ============
        uint32_t Pfull = P0;
        int kth = need;
        uint32_t* myh = &hw[w * 256];
        for (int pass = 1; pass < 4; ++pass) {
            int shift = 24 - 8 * pass;
            for (int i2 = t; i2 < NWAVE * 256; i2 += 1024) hw[i2] = 0;
            __syncthreads();
            uint32_t pmask = 0xFFFFFFFFu << (shift + 8);
            for (int p4 = t; p4 < QC4; p4 += 1024) {
                float4 v = base4[p4];
                uint32_t kk[4] = {fkey(v.x), fkey(v.y), fkey(v.z), fkey(v.w)};
#pragma unroll
                for (int c = 0; c < 4; ++c)
                    if ((kk[c] & pmask) == Pfull) atomicAdd(&myh[(kk[c] >> shift) & 255u], 1u);
            }
            __syncthreads();
            if (t < 256) {
                uint32_t ssum = 0;
#pragma unroll
                for (int ww = 0; ww < NWAVE; ++ww) ssum += hw[ww * 256 + t];
                scn[t] = ssum;
            }
            __syncthreads();
            if (t < 64) pick_boundary(scn, kth, lane, &sP, &sNeed, &sCnt);
            __syncthreads();
            Pfull |= (sP << shift);
            kth = sNeed;
        }
        if (t == 0) { cntTop = 0; cntE = 0; }
        __syncthreads();
        for (int p4 = t; p4 < QC4; p4 += 1024) {
            float4 v = base4[p4];
            uint32_t kk[4] = {fkey(v.x), fkey(v.y), fkey(v.z), fkey(v.w)};
#pragma unroll
            for (int c = 0; c < 4; ++c) {
                if (kk[c] > Pfull) {
                    int pos = atomicAdd(&cntTop, 1);
                    cKey[pos] = kk[c]; cIdx[pos] = 4 * p4 + c;
                } else if (kk[c] == Pfull) {
                    int pos = atomicAdd(&cntE, 1);
                    if (pos < CAP) candI[0][pos] = 4 * p4 + c;
                }
            }
        }
        __syncthreads();
        int cgt2 = cntTop;   // == TOPK - kth
        int ne = cntE;
        if (ne <= CAP) {
            for (int j2 = t; j2 < ne; j2 += 1024) {
                int my = candI[0][j2];
                int rank = 0;
                for (int m = 0; m < ne; ++m) rank += (candI[0][m] < my);
                if (rank < kth) { cKey[cgt2 + rank] = Pfull; cIdx[cgt2 + rank] = my; }
            }
            __syncthreads();
        } else {
            int prevMin = -1;
            for (int r = 0; r < kth; ++r) {
                if (t == 0) sMin = 0x7fffffff;
                __syncthreads();
                int loc = 0x7fffffff;
                for (int p4 = t; p4 < QC4; p4 += 1024) {
                    float4 v = base4[p4];
                    uint32_t kk[4] = {fkey(v.x), fkey(v.y), fkey(v.z), fkey(v.w)};
#pragma unroll
                    for (int c = 0; c < 4; ++c) {
                        int idx = 4 * p4 + c;
                        if (kk[c] == Pfull && idx > prevMin) loc = min(loc, idx);
                    }
                }
                atomicMin(&sMin, loc);
                __syncthreads();
                prevMin = sMin;
                if (t == 0) { cKey[cgt2 + r] = Pfull; cIdx[cgt2 + r] = prevMin; }
                __syncthreads();
            }
        }
    }

    // ---- rank 50 winners (key desc, index asc) and emit ----
    if (t < TOPK) {
        uint32_t myk = cKey[t]; int myi = cIdx[t];
        int rank = 0;
        for (int m = 0; m < TOPK; ++m) {
            uint32_t ok = cKey[m]; int oi = cIdx[m];
            rank += (ok > myk) || (ok == myk && oi < myi);
        }
        uint32_t u = (myk >> 31) ? (myk & 0x7fffffffu) : ~myk;
        float val = __uint_as_float(u);
        int q = myi / CC;
        int label = myi - q * CC;
        out[OFF_SCORES + b * TOPK + rank] = 1.0f / (1.0f + expf(-val));
        out[OFF_LABELS + b * TOPK + rank] = (float)label;
        wsQ[b * TOPK + rank] = q;
        const float* bbp = bbox + ((size_t)(b * QQ + q)) * 4;
        float cx = bbp[0], cy = bbp[1], bw = bbp[2], bh = bbp[3];
        float ih = (float)tsz[b * 2 + 0];
        float iw = (float)tsz[b * 2 + 1];
        float* bo = out + OFF_BOXES + ((size_t)(b * TOPK + rank)) * 4;
        bo[0] = (cx - 0.5f * bw) * iw;
        bo[1] = (cy - 0.5f * bh) * ih;
        bo[2] = (cx + 0.5f * bw) * iw;
        bo[3] = (cy + 0.5f * bh) * ih;
    }
    if (t == 0) {
        const float* ap = actions + (size_t)b * 10;
        float bv = ap[0]; int bi = 0;
        for (int i = 1; i < 10; ++i) { if (ap[i] > bv) { bv = ap[i]; bi = i; } }
        out[OFF_LA + b] = (float)bi;
    }
}

// ---------------- per-(b,rank) mask DCT + threshold + interms (R4/R5-verified, verbatim) -------
__global__ __launch_bounds__(256) void mask_kernel(const float* __restrict__ vec,
                                                   const float* __restrict__ interms,
                                                   const int* __restrict__ wsQ,
                                                   const float* __restrict__ wsD,
                                                   const int* __restrict__ wsZZ,
                                                   float* __restrict__ out) {
    int j = blockIdx.x;      // rank 0..49
    int b = blockIdx.y;      // batch
    int t = threadIdx.x;

    __shared__ float sT[23 * 128];
    __shared__ float sB[23 * 24];
    __shared__ float redv[4];
    __shared__ int   redi[4];
    __shared__ float redmn[4], redmx[4];

    int q = wsQ[b * TOPK + j];

    for (int i = t; i < 23 * 24; i += 256) sB[i] = 0.0f;
    __syncthreads();

    // scatter the 256 kept coefficients into zigzag positions (k+l <= 22)
    {
        int kl = wsZZ[t];
        float x = vec[((size_t)(b * QQ + q)) * NKEEP + t];
        sB[(kl >> 5) * 24 + (kl & 31)] = x;
    }

    // interms argmax/max over 91 classes (sigmoid is monotone)
    int lane = t & 63, w = t >> 6;
    {
        float x = (t < CC) ? interms[((size_t)(b * QQ + q)) * CC + t] : -INFINITY;
        int xi = (t < CC) ? t : 0x7fffffff;
#pragma unroll
        for (int off = 32; off >= 1; off >>= 1) {
            float ov = __shfl_down(x, off);
            int   oi = __shfl_down(xi, off);
            bool better = (ov > x) || (ov == x && oi < xi);
            x = better ? ov : x;
            xi = better ? oi : xi;
        }
        if (lane == 0) { redv[w] = x; redi[w] = xi; }
    }
    __syncthreads();   // guards sB scatter + redv/redi

    if (t == 0) {
        float gv = redv[0]; int gi = redi[0];
        for (int k = 1; k < 4; ++k) {
            bool better = (redv[k] > gv) || (redv[k] == gv && redi[k] < gi);
            gv = better ? redv[k] : gv;
            gi = better ? redi[k] : gi;
        }
        out[OFF_SI + (size_t)b * TOPK + j] = 1.0f / (1.0f + expf(-gv));
        out[OFF_LI + (size_t)b * TOPK + j] = (float)gi;
    }

    // stage 1: T[l][n] = sum_{k <= 22-l} D[k][n] * B[k][l]  (triangular; D from global/L1)
    {
        int n = t & 127, h = t >> 7;
        float Dn[23];
#pragma unroll
        for (int k = 0; k < 23; ++k) Dn[k] = wsD[k * 128 + n];
#define S1L(L) { float a1 = 0.0f; \
    _Pragma("unroll") \
    for (int k = 0; k <= 22 - (L); ++k) a1 += Dn[k] * sB[k * 24 + (L)]; \
    sT[(L) * 128 + n] = a1; }
        if (h == 0) {
            S1L(0) S1L(2) S1L(4) S1L(6) S1L(8) S1L(10)
            S1L(12) S1L(14) S1L(16) S1L(18) S1L(20) S1L(22)
        } else {
            S1L(1) S1L(3) S1L(5) S1L(7) S1L(9) S1L(11)
            S1L(13) S1L(15) S1L(17) S1L(19) S1L(21)
        }
#undef S1L
    }
    __syncthreads();

    // stage 2: out[n][m] = sum_l T[l][n] * D[l][m]  (T from LDS broadcast, D from global/L1)
    int tr = t >> 4, tc = t & 15;
    float acc[8][8];
#pragma unroll
    for (int a = 0; a < 8; ++a)
#pragma unroll
        for (int c = 0; c < 8; ++c) acc[a][c] = 0.0f;

#pragma unroll 4
    for (int l = 0; l < 23; ++l) {
        const float4 Ta = *(const float4*)&sT[l * 128 + tr * 8];
        const float4 Tb = *(const float4*)&sT[l * 128 + tr * 8 + 4];
        const float4 Da = *(const float4*)&wsD[l * 128 + tc * 8];
        const float4 Db = *(const float4*)&wsD[l * 128 + tc * 8 + 4];
        float Tv[8] = {Ta.x, Ta.y, Ta.z, Ta.w, Tb.x, Tb.y, Tb.z, Tb.w};
        float Dv[8] = {Da.x, Da.y, Da.z, Da.w, Db.x, Db.y, Db.z, Db.w};
#pragma unroll
        for (int a = 0; a < 8; ++a)
#pragma unroll
            for (int c = 0; c < 8; ++c) acc[a][c] += Tv[a] * Dv[c];
    }

    // block min/max
    float mn = acc[0][0], mx = acc[0][0];
#pragma unroll
    for (int a = 0; a < 8; ++a)
#pragma unroll
        for (int c = 0; c < 8; ++c) {
            mn = fminf(mn, acc[a][c]);
            mx = fmaxf(mx, acc[a][c]);
        }
#pragma unroll
    for (int off = 32; off >= 1; off >>= 1) {
        mn = fminf(mn, __shfl_down(mn, off));
        mx = fmaxf(mx, __shfl_down(mx, off));
    }
    if (lane == 0) { redmn[w] = mn; redmx[w] = mx; }
    __syncthreads();
    float gmn = fminf(fminf(redmn[0], redmn[1]), fminf(redmn[2], redmn[3]));
    float gmx = fmaxf(fmaxf(redmx[0], redmx[1]), fmaxf(redmx[2], redmx[3]));
    float thr = 0.5f * (gmx + gmn);

    size_t bse = OFF_MASKS + ((size_t)(b * TOPK + j)) * 16384 + (size_t)tc * 8;
#pragma unroll
    for (int a = 0; a < 8; ++a) {
        int n = tr * 8 + a;
        float4 w0 = make_float4(acc[a][0] > thr ? 1.0f : 0.0f,
                                acc[a][1] > thr ? 1.0f : 0.0f,
                                acc[a][2] > thr ? 1.0f : 0.0f,
                                acc[a][3] > thr ? 1.0f : 0.0f);
        float4 w1 = make_float4(acc[a][4] > thr ? 1.0f : 0.0f,
                                acc[a][5] > thr ? 1.0f : 0.0f,
                                acc[a][6] > thr ? 1.0f : 0.0f,
                                acc[a][7] > thr ? 1.0f : 0.0f);
        *(float4*)&out[bse + (size_t)n * 128]     = w0;
        *(float4*)&out[bse + (size_t)n * 128 + 4] = w1;
    }
}

extern "C" void kernel_launch(void* const* d_in, const int* in_sizes, int n_in,
                              void* d_out, int out_size, void* d_ws, size_t ws_size,
                              hipStream_t stream) {
    const float* logits  = (const float*)d_in[0];
    const float* bbox    = (const float*)d_in[1];
    const float* vec     = (const float*)d_in[2];
    const float* interms = (const float*)d_in[3];
    const float* actions = (const float*)d_in[4];
    const int*   tsz     = (const int*)d_in[5];
    float* out = (float*)d_out;

    float* wsD  = (float*)d_ws;            // 23*128 = 2944 floats
    int*   wsZZ = (int*)(wsD + 2944);      // 256 ints
    int*   wsQ  = wsZZ + 256;              // 1600 ints

    hipLaunchKernelGGL(topk_select, dim3(BB), dim3(1024), 0, stream,
                       logits, bbox, actions, tsz, out, wsQ, wsD, wsZZ);
    hipLaunchKernelGGL(mask_kernel, dim3(TOPK, BB), dim3(256), 0, stream,
                       vec, interms, wsQ, wsD, wsZZ, out);
}